// Round 14
// baseline (128.101 us; speedup 1.0000x reference)
//
#include <hip/hip_runtime.h>
#include <hip/hip_bf16.h>
#include <math.h>

// Problem constants (B=8, T=1024, D=512, LEFT=16, RIGHT=0)
constexpr int Tn = 1024;
constexpr int Dn = 512;
constexpr int BT = 8192;
constexpr int WIN = 16;

typedef short bs8 __attribute__((ext_vector_type(8)));     // 8 bf16 (bit pattern)
typedef short sh4 __attribute__((ext_vector_type(4)));     // 4 bf16 (8 B)
typedef unsigned short us8 __attribute__((ext_vector_type(8)));
typedef float fx4 __attribute__((ext_vector_type(4)));

// bf16 helpers: HW conversion (v_cvt_pk_bf16_f32 via compiler), RNE
__device__ inline unsigned short f2bf(float f) {
    union { __hip_bfloat16 b; unsigned short u; } c;
    c.b = __float2bfloat16(f);
    return c.u;
}
__device__ inline float bf2f(unsigned short h) {
    return __uint_as_float(((unsigned int)h) << 16);
}
// chunk-swizzle involution: spreads ds_read banks (bijective per 4-chunk row)
__device__ inline int fsw(int m) { return (m & 3) ^ ((m >> 2) & 3); }

// ---------------------------------------------------------------------------
// Kernel 1 (wprep):
//   [0,512):   split-K(8) partials of G = M @ C^T (K-chunk 64) -> Gp.
//              After writing, ticket = atomicAdd(cnt). Tickets [448,512)
//              spin until cnt==512, then pack 8 G-rows each into Bt[0,512):
//              Bt[b][a]=hi(G[a][b]), Bt[b][512+a]=lo.  (Deadlock-free: every
//              spinner already incremented; all 576 blocks co-resident.)
//   [512,576): split+transpose V (hi) -> Bt rows [512,1024)
// ---------------------------------------------------------------------------
__global__ __launch_bounds__(256) void wprep(
    const float* __restrict__ Mw, const float* __restrict__ Cw,
    const float* __restrict__ Vw,
    float* __restrict__ Gp, short* __restrict__ Bt,
    unsigned int* __restrict__ cnt)
{
    __shared__ float smem[64 * 65];
    __shared__ unsigned int tick_s;
    const int blk = blockIdx.x;
    const int tid = threadIdx.x;

    if (blk < 512) {
        // ---- g_partial: Gp[kc][b][a] = sum_{j in 64-chunk} M[a,j] C[b,j] ----
        float* As = smem;              // [64][17]
        float* Bs = smem + 64 * 17;
        const int kch = blk >> 6;           // 0..7
        const int r6 = blk & 63;
        const int b0 = (r6 & 7) * 64;
        const int a0 = (r6 >> 3) * 64;
        const int tx = tid & 15, ty = tid >> 4;

        float acc[4][4] = {};
        for (int j0 = kch * 64; j0 < kch * 64 + 64; j0 += 16) {
            const int r = tid >> 2;
            const int c = (tid & 3) * 4;
            const float4 a = *(const float4*)(Mw + (size_t)(a0 + r) * Dn + j0 + c);
            As[r * 17 + c + 0] = a.x; As[r * 17 + c + 1] = a.y;
            As[r * 17 + c + 2] = a.z; As[r * 17 + c + 3] = a.w;
            const float4 b = *(const float4*)(Cw + (size_t)(b0 + r) * Dn + j0 + c);
            Bs[r * 17 + c + 0] = b.x; Bs[r * 17 + c + 1] = b.y;
            Bs[r * 17 + c + 2] = b.z; Bs[r * 17 + c + 3] = b.w;
            __syncthreads();
            #pragma unroll
            for (int kk = 0; kk < 16; ++kk) {
                float av[4], bv[4];
                #pragma unroll
                for (int i = 0; i < 4; ++i) av[i] = As[(ty * 4 + i) * 17 + kk];
                #pragma unroll
                for (int j = 0; j < 4; ++j) bv[j] = Bs[(tx * 4 + j) * 17 + kk];
                #pragma unroll
                for (int i = 0; i < 4; ++i)
                    #pragma unroll
                    for (int j = 0; j < 4; ++j)
                        acc[i][j] += av[i] * bv[j];
            }
            __syncthreads();
        }
        #pragma unroll
        for (int j = 0; j < 4; ++j) {
            const int b = b0 + tx * 4 + j;
            float4 col = make_float4(acc[0][j], acc[1][j], acc[2][j], acc[3][j]);
            *(float4*)(Gp + ((size_t)kch * 512 + b) * 512 + a0 + ty * 4) = col;
        }

        // ---- release-increment; last 64 finishers pack G -> Bt ----
        __threadfence();                       // publish Gp device-wide
        if (tid == 0) tick_s = atomicAdd(cnt, 1u);
        __syncthreads();
        const unsigned int t = tick_s;
        if (t >= 448u) {
            if (tid == 0) {
                while (atomicAdd(cnt, 0u) < 512u) __builtin_amdgcn_s_sleep(8);
            }
            __syncthreads();
            __threadfence();                   // acquire: see all Gp stores
            const int pid = (int)(t - 448u);   // 0..63 -> rows b = pid*8..+8
            #pragma unroll
            for (int q = 0; q < 2; ++q) {
                const int e = q * 256 + tid;   // 0..511 chunk index
                const int b = pid * 8 + (e >> 6);
                const int a8 = (e & 63) * 8;
                float s[8] = {};
                #pragma unroll
                for (int kc = 0; kc < 8; ++kc) {
                    const float* p = Gp + ((size_t)kc * 512 + b) * 512 + a8;
                    const float4 p0 = *(const float4*)p;
                    const float4 p1 = *(const float4*)(p + 4);
                    s[0] += p0.x; s[1] += p0.y; s[2] += p0.z; s[3] += p0.w;
                    s[4] += p1.x; s[5] += p1.y; s[6] += p1.z; s[7] += p1.w;
                }
                union { bs8 v; unsigned short u[8]; } hi, lo;
                #pragma unroll
                for (int j = 0; j < 8; ++j) {
                    const unsigned short h = f2bf(s[j]);
                    hi.u[j] = h;
                    lo.u[j] = f2bf(s[j] - bf2f(h));
                }
                short* base = Bt + (size_t)b * 1024 + a8;
                *(bs8*)base         = hi.v;
                *(bs8*)(base + 512) = lo.v;
            }
        }
    } else {
        // ---- split_v: Bt[512+n][k] = hi(V[k][n]) ----
        float* tile = smem;            // [64][65]
        const int z = blk - 512;
        const int k0 = (z & 7) * 64;
        const int n0 = (z >> 3) * 64;
        #pragma unroll
        for (int rr = 0; rr < 4; ++rr) {
            const int row = (tid >> 4) * 4 + rr;
            const int col = (tid & 15) * 4;
            const float4 w = *(const float4*)(Vw + (size_t)(k0 + row) * Dn + n0 + col);
            tile[row * 65 + col + 0] = w.x; tile[row * 65 + col + 1] = w.y;
            tile[row * 65 + col + 2] = w.z; tile[row * 65 + col + 3] = w.w;
        }
        __syncthreads();
        const int n  = tid >> 2;
        const int ks = (tid & 3) * 16;
        union { bs8 v; unsigned short u[8]; } hi0, hi1;
        #pragma unroll
        for (int i = 0; i < 8; ++i) {
            hi0.u[i] = f2bf(tile[(ks + i) * 65 + n]);
            hi1.u[i] = f2bf(tile[(ks + 8 + i) * 65 + n]);
        }
        short* base = Bt + (size_t)(512 + n0 + n) * 1024 + k0 + ks;
        *(bs8*)base       = hi0.v;
        *(bs8*)(base + 8) = hi1.v;
    }
}

// ---------------------------------------------------------------------------
// Kernel 2: bf16 MFMA GEMM, reg-staged f32 A, single-barrier dbuf (R12
// schedule — loads issued BEFORE compute, so the barrier drain is covered).
//   Y (blocks 0..255):  K=512, 3 terms/chunk -> Yh/Yl bf16 planes
//   V (blocks 256..511): K=512, hi term     -> Vt transposed bf16 [512][8192]
// 128x128 tile; 8 waves as 2(wr) x 4(wc), each 64x32 (acc[4][2]).
// ---------------------------------------------------------------------------
__global__ __launch_bounds__(512, 4) void gemm_mfma(
    const float* __restrict__ X, const short* __restrict__ Bt,
    short* __restrict__ Yh, short* __restrict__ Yl, short* __restrict__ Vt)
{
    // [buf][plane]: 0=Ahi 1=Alo 2=B0(Ghi/Vhi) 3=B1(Glo); 8KB planes, 64KB total
    __shared__ short lds[2][4][128 * 32];

    const int lin = blockIdx.x;              // 0..511
    const int xcd = lin & 7;
    const int s   = lin >> 3;                // 0..63
    int mt, nt;
    if (s < 32) {                            // Y blocks first
        mt = xcd * 8 + (s & 7);
        nt = s >> 3;                         // 0..3
    } else {
        const int v = s - 32;
        mt = xcd * 8 + (v & 7);
        nt = 4 + (v >> 3);                   // 4..7
    }
    const int m0 = mt * 128, n0g = nt * 128;
    const int slab = nt >> 2;                // 0=Y, 1=V

    const int tid = threadIdx.x;
    const int ln  = tid & 63;
    const int wid = tid >> 6;                // 0..7
    const int wr = wid >> 2, wc = wid & 3;   // 2 x 4 waves
    const int lrow = ln & 15;
    const int lkb  = ln >> 4;                // 0..3

    fx4 acc[4][2] = {};

    // A staging geometry: thread -> (row, 8-elem chunk)
    const int ar = tid >> 2;                 // 0..127
    const int aj = tid & 3;                  // chunk 0..3
    const int aoff = ar * 32 + (aj ^ fsw(ar)) * 8;   // swizzled LDS offset
    const float* xrow = X + (size_t)(m0 + ar) * 512 + aj * 8;

    // B staging geometry (pre-swizzled global source, linear LDS dest)
    const int bnr = tid >> 2, bjj = tid & 3;
    const int bjs = bjj ^ fsw(bnr);
    const size_t bsrc = (size_t)(n0g + bnr) * 1024 + bjs * 8;

    auto stageB = [&](int bi, int k0) {
        __builtin_amdgcn_global_load_lds(
            (const __attribute__((address_space(1))) unsigned int*)(Bt + bsrc + k0),
            (__attribute__((address_space(3))) unsigned int*)(&lds[bi][2][tid * 8]), 16, 0, 0);
        if (slab == 0)
            __builtin_amdgcn_global_load_lds(
                (const __attribute__((address_space(1))) unsigned int*)(Bt + bsrc + 512 + k0),
                (__attribute__((address_space(3))) unsigned int*)(&lds[bi][3][tid * 8]), 16, 0, 0);
    };
    auto writeA = [&](int bi, const float4& f0, const float4& f1) {
        const float xs[8] = {f0.x, f0.y, f0.z, f0.w, f1.x, f1.y, f1.z, f1.w};
        union { bs8 v; unsigned short u[8]; } hi, lo;
        #pragma unroll
        for (int e = 0; e < 8; ++e) {
            const unsigned short h = f2bf(xs[e]);
            hi.u[e] = h;
            lo.u[e] = f2bf(xs[e] - bf2f(h));
        }
        *(bs8*)(&lds[bi][0][aoff]) = hi.v;
        if (slab == 0) *(bs8*)(&lds[bi][1][aoff]) = lo.v;
    };
    auto compute = [&](int bi) {
        bs8 ah[4], al[4], b0[2], b1[2];
        #pragma unroll
        for (int mf = 0; mf < 4; ++mf) {
            const int m = wr * 64 + mf * 16 + lrow;
            const int off = m * 32 + ((lkb ^ fsw(m)) * 8);
            ah[mf] = *(const bs8*)(&lds[bi][0][off]);
            if (slab == 0) al[mf] = *(const bs8*)(&lds[bi][1][off]);
        }
        #pragma unroll
        for (int nf = 0; nf < 2; ++nf) {
            const int n = wc * 32 + nf * 16 + lrow;
            const int off = n * 32 + ((lkb ^ fsw(n)) * 8);
            b0[nf] = *(const bs8*)(&lds[bi][2][off]);
            if (slab == 0) b1[nf] = *(const bs8*)(&lds[bi][3][off]);
        }
        #pragma unroll
        for (int mf = 0; mf < 4; ++mf)
            #pragma unroll
            for (int nf = 0; nf < 2; ++nf) {
                acc[mf][nf] = __builtin_amdgcn_mfma_f32_16x16x32_bf16(
                    ah[mf], b0[nf], acc[mf][nf], 0, 0, 0);
                if (slab == 0) {
                    acc[mf][nf] = __builtin_amdgcn_mfma_f32_16x16x32_bf16(
                        al[mf], b0[nf], acc[mf][nf], 0, 0, 0);
                    acc[mf][nf] = __builtin_amdgcn_mfma_f32_16x16x32_bf16(
                        ah[mf], b1[nf], acc[mf][nf], 0, 0, 0);
                }
            }
    };

    // prologue: chunk 0 into buf 0
    {
        const float4 f0 = *(const float4*)xrow;
        const float4 f1 = *(const float4*)(xrow + 4);
        stageB(0, 0);
        writeA(0, f0, f1);
    }
    __syncthreads();

    for (int it = 0; it < 16; ++it) {
        const int bi = it & 1;
        float4 n0, n1;
        if (it < 15) {
            const float* p = xrow + (it + 1) * 32;
            n0 = *(const float4*)p;
            n1 = *(const float4*)(p + 4);
            stageB(bi ^ 1, (it + 1) * 32);
        }
        compute(bi);
        if (it < 15) writeA(bi ^ 1, n0, n1);
        __syncthreads();
    }

    if (slab == 0) {
        // Y epilogue: split into Yh/Yl bf16 planes
        #pragma unroll
        for (int mf = 0; mf < 4; ++mf) {
            #pragma unroll
            for (int nf = 0; nf < 2; ++nf) {
                const int col = n0g + wc * 32 + nf * 16 + lrow;
                #pragma unroll
                for (int r = 0; r < 4; ++r) {
                    const int row = m0 + wr * 64 + mf * 16 + lkb * 4 + r;
                    const float v = acc[mf][nf][r];
                    const unsigned short h = f2bf(v);
                    Yh[(size_t)row * 512 + col] = (short)h;
                    Yl[(size_t)row * 512 + col] = (short)f2bf(v - bf2f(h));
                }
            }
        }
    } else {
        // V epilogue: transposed store Vt[d][token], 4 rows -> one 8B store
        #pragma unroll
        for (int mf = 0; mf < 4; ++mf) {
            #pragma unroll
            for (int nf = 0; nf < 2; ++nf) {
                const int c = (n0g - 512) + wc * 32 + nf * 16 + lrow;   // d
                const int row0 = m0 + wr * 64 + mf * 16 + lkb * 4;
                sh4 v4;
                #pragma unroll
                for (int r = 0; r < 4; ++r) v4[r] = (short)f2bf(acc[mf][nf][r]);
                *(sh4*)(Vt + (size_t)c * 8192 + row0) = v4;
            }
        }
    }
}

// ---------------------------------------------------------------------------
// Kernel 3: banded attention via MFMA. One wave per 16-token strip.
//   S[i][j] = Y[t0+i] . X[t0-15+j]; Y = Yh+Yl planes, X split in-lane from
//   exact f32 (HW cvt). Vt B-fragments gathered into registers BEFORE the QK
//   phase (independent loads; latency hidden under QK compute).
//   Band: src<0 slots -> logit 0 exactly (exp(0) in denominator), no V term.
// ---------------------------------------------------------------------------
__global__ __launch_bounds__(64, 1) void attn_mfma(
    const float* __restrict__ X,
    const short* __restrict__ Yh, const short* __restrict__ Yl,
    const short* __restrict__ Vt, float* __restrict__ out)
{
    __shared__ short Plds[16 * 32];

    const int lin = blockIdx.x;                   // 0..511
    const int strip = (lin & 7) * 64 + (lin >> 3);  // XCD swizzle (512=8x64)
    const int t0 = strip * 16;
    const int bat = t0 >> 10;
    const int tt0 = t0 & 1023;
    const int l  = threadIdx.x;                   // 0..63
    const int lr = l & 15;
    const int lg = l >> 4;                        // 0..3

    // ---- hoisted PV B-fragments (OOB reads hit finite ws bytes only where
    //      P=0) ----
    const long svt = (long)bat * 1024 + (tt0 - 15 + lg * 8);
    bs8 bv[32];
    #pragma unroll
    for (int nf = 0; nf < 32; ++nf)
        bv[nf] = *(const bs8*)(Vt + (long)(nf * 16 + lr) * 8192 + svt);

    const size_t yrow = (size_t)(t0 + lr) * 512 + lg * 8;
    const int srcl0 = tt0 - 15 + lr;              // local src for j=lr
    const int srcl1 = tt0 + 1 + lr;               // local src for j=lr+16
    const int r0c = srcl0 < 0 ? 0 : srcl0;
    const int r1c = srcl1 > 1023 ? 1023 : srcl1;  // only j=31 (masked) hits 1024
    const size_t xrow0 = ((size_t)(bat * 1024 + r0c)) * 512 + lg * 8;
    const size_t xrow1 = ((size_t)(bat * 1024 + r1c)) * 512 + lg * 8;

    fx4 s0a = {0,0,0,0}, s0b = {0,0,0,0};
    fx4 s1a = {0,0,0,0}, s1b = {0,0,0,0};
    #pragma unroll
    for (int k0 = 0; k0 < 512; k0 += 32) {
        const bs8 ah = *(const bs8*)(Yh + yrow + k0);
        const bs8 al = *(const bs8*)(Yl + yrow + k0);
        const float4 p0a = *(const float4*)(X + xrow0 + k0);
        const float4 p0b = *(const float4*)(X + xrow0 + k0 + 4);
        const float4 p1a = *(const float4*)(X + xrow1 + k0);
        const float4 p1b = *(const float4*)(X + xrow1 + k0 + 4);
        const float x0s[8] = {p0a.x,p0a.y,p0a.z,p0a.w,p0b.x,p0b.y,p0b.z,p0b.w};
        const float x1s[8] = {p1a.x,p1a.y,p1a.z,p1a.w,p1b.x,p1b.y,p1b.z,p1b.w};
        union { bs8 v; unsigned short u[8]; } bh0, bl0, bh1, bl1;
        #pragma unroll
        for (int e = 0; e < 8; ++e) {
            unsigned short h = f2bf(x0s[e]);
            bh0.u[e] = h; bl0.u[e] = f2bf(x0s[e] - bf2f(h));
            h = f2bf(x1s[e]);
            bh1.u[e] = h; bl1.u[e] = f2bf(x1s[e] - bf2f(h));
        }
        s0a = __builtin_amdgcn_mfma_f32_16x16x32_bf16(ah, bh0.v, s0a, 0, 0, 0);
        s0b = __builtin_amdgcn_mfma_f32_16x16x32_bf16(al, bh0.v, s0b, 0, 0, 0);
        s0b = __builtin_amdgcn_mfma_f32_16x16x32_bf16(ah, bl0.v, s0b, 0, 0, 0);
        s1a = __builtin_amdgcn_mfma_f32_16x16x32_bf16(ah, bh1.v, s1a, 0, 0, 0);
        s1b = __builtin_amdgcn_mfma_f32_16x16x32_bf16(al, bh1.v, s1b, 0, 0, 0);
        s1b = __builtin_amdgcn_mfma_f32_16x16x32_bf16(ah, bl1.v, s1b, 0, 0, 0);

        // concat copy: rows t0..t0+15 from the same loads (exact f32)
        if (lr == 15) {               // xrow0 == row t0
            float* o = out + (size_t)t0 * 1024 + k0 + lg * 8;
            *(float4*)o       = p0a;
            *(float4*)(o + 4) = p0b;
        } else {                      // xrow1 == row t0+1+lr  (lr<15)
            float* o = out + (size_t)(t0 + 1 + lr) * 1024 + k0 + lg * 8;
            *(float4*)o       = p1a;
            *(float4*)(o + 4) = p1b;
        }
    }

    // ---- band mask + softmax (per lane: 4 rows x 2 cols) ----
    #pragma unroll
    for (int r = 0; r < 4; ++r) {
        const int i = lg * 4 + r;
        const int d0 = lr - i;            // w-offset for j=lr
        const int d1 = lr + 16 - i;       // w-offset for j=lr+16
        const bool in0 = (d0 >= 0) && (d0 <= 15);
        const bool in1 = (d1 >= 0) && (d1 <= 15);
        const bool z0 = srcl0 < 0;        // src<0 -> logit 0 exactly
        float v0 = z0 ? 0.0f : (s0a[r] + s0b[r]);
        float v1 = s1a[r] + s1b[r];
        v0 = in0 ? v0 : -3.0e38f;
        v1 = in1 ? v1 : -3.0e38f;
        float m = fmaxf(v0, v1);
        #pragma unroll
        for (int st = 1; st < 16; st <<= 1) m = fmaxf(m, __shfl_xor(m, st, 64));
        const float e0 = in0 ? __expf(v0 - m) : 0.0f;
        const float e1 = in1 ? __expf(v1 - m) : 0.0f;
        float den = e0 + e1;
        #pragma unroll
        for (int st = 1; st < 16; st <<= 1) den += __shfl_xor(den, st, 64);
        const float inv = 1.0f / den;
        const float p0 = (in0 && !z0) ? e0 * inv : 0.0f;
        const float p1 = in1 ? e1 * inv : 0.0f;
        Plds[i * 32 + lr]      = (short)f2bf(p0);
        Plds[i * 32 + lr + 16] = (short)f2bf(p1);
    }
    __syncthreads();

    // ---- PV: answer(16x512) = P(16x32) @ V'_window(32x512), B pre-loaded ----
    const bs8 pa = *(const bs8*)(Plds + lr * 32 + lg * 8);
    #pragma unroll
    for (int nf = 0; nf < 32; ++nf) {
        const int d = nf * 16 + lr;
        fx4 c = {0, 0, 0, 0};
        c = __builtin_amdgcn_mfma_f32_16x16x32_bf16(pa, bv[nf], c, 0, 0, 0);
        #pragma unroll
        for (int r = 0; r < 4; ++r)
            out[(size_t)(t0 + lg * 4 + r) * 1024 + 512 + d] = c[r];
    }
}

// ---------------------------------------------------------------------------
extern "C" void kernel_launch(void* const* d_in, const int* in_sizes, int n_in,
                              void* d_out, int out_size, void* d_ws, size_t ws_size,
                              hipStream_t stream)
{
    const float* X  = (const float*)d_in[0];
    const float* Mw = (const float*)d_in[1];
    const float* Cw = (const float*)d_in[2];
    const float* Vw = (const float*)d_in[3];
    float* out = (float*)d_out;

    // ws layout (34 MB total), Vt LAST among bf16 planes (OOB guard reads
    // land in Yl / the counter, both finite):
    short* Bt = (short*)d_ws;                                   // 2 MB
    float* Gp = (float*)(Bt + (size_t)1024 * 1024);             // 8 MB
    short* Yh = (short*)(Gp + (size_t)8 * 512 * 512);           // 8 MB
    short* Yl = Yh + (size_t)BT * 512;                          // 8 MB
    short* Vt = Yl + (size_t)BT * 512;                          // 8 MB
    unsigned int* cnt = (unsigned int*)(Vt + (size_t)BT * 512); // 4 B

    hipMemsetAsync(cnt, 0, 4, stream);   // deterministic counter reset
    wprep<<<576, 256, 0, stream>>>(Mw, Cw, Vw, Gp, Bt, cnt);
    gemm_mfma<<<512, 512, 0, stream>>>(X, Bt, Yh, Yl, Vt);
    attn_mfma<<<512, 64, 0, stream>>>(X, Yh, Yl, Vt, out);
}

// Round 15
// 64.880 us; speedup vs baseline: 1.9744x; 1.9744x over previous
//
#include <hip/hip_runtime.h>
#include <hip/hip_bf16.h>
#include <math.h>

// Problem constants (B=8, T=1024, D=512, LEFT=16, RIGHT=0)
constexpr int Tn = 1024;
constexpr int Dn = 512;
constexpr int BT = 8192;
constexpr int WIN = 16;

typedef short bs8 __attribute__((ext_vector_type(8)));     // 8 bf16 (bit pattern)
typedef short sh4 __attribute__((ext_vector_type(4)));     // 4 bf16 (8 B)
typedef unsigned short us8 __attribute__((ext_vector_type(8)));
typedef float fx4 __attribute__((ext_vector_type(4)));

// bf16 helpers: HW conversion (v_cvt_pk_bf16_f32 via compiler), RNE
__device__ inline unsigned short f2bf(float f) {
    union { __hip_bfloat16 b; unsigned short u; } c;
    c.b = __float2bfloat16(f);
    return c.u;
}
__device__ inline float bf2f(unsigned short h) {
    return __uint_as_float(((unsigned int)h) << 16);
}
// chunk-swizzle involution: spreads ds_read banks (bijective per 4-chunk row)
__device__ inline int fsw(int m) { return (m & 3) ^ ((m >> 2) & 3); }

// ---------------------------------------------------------------------------
// Kernel 1 (wprep):
//   [0,512):   split-K(8) partials of G = M @ C^T (K-chunk 64)
//   [512,576): split+transpose V (hi) -> Bt rows [512,1024)
// ---------------------------------------------------------------------------
__global__ __launch_bounds__(256) void wprep(
    const float* __restrict__ Mw, const float* __restrict__ Cw,
    const float* __restrict__ Vw,
    float* __restrict__ Gp, short* __restrict__ Bt)
{
    __shared__ float smem[64 * 65];
    const int blk = blockIdx.x;
    const int tid = threadIdx.x;

    if (blk < 512) {
        // ---- g_partial: Gp[kc][b][a] = sum_{j in 64-chunk} M[a,j] C[b,j] ----
        float* As = smem;              // [64][17]
        float* Bs = smem + 64 * 17;
        const int kch = blk >> 6;           // 0..7
        const int r6 = blk & 63;
        const int b0 = (r6 & 7) * 64;
        const int a0 = (r6 >> 3) * 64;
        const int tx = tid & 15, ty = tid >> 4;

        float acc[4][4] = {};
        for (int j0 = kch * 64; j0 < kch * 64 + 64; j0 += 16) {
            const int r = tid >> 2;
            const int c = (tid & 3) * 4;
            const float4 a = *(const float4*)(Mw + (size_t)(a0 + r) * Dn + j0 + c);
            As[r * 17 + c + 0] = a.x; As[r * 17 + c + 1] = a.y;
            As[r * 17 + c + 2] = a.z; As[r * 17 + c + 3] = a.w;
            const float4 b = *(const float4*)(Cw + (size_t)(b0 + r) * Dn + j0 + c);
            Bs[r * 17 + c + 0] = b.x; Bs[r * 17 + c + 1] = b.y;
            Bs[r * 17 + c + 2] = b.z; Bs[r * 17 + c + 3] = b.w;
            __syncthreads();
            #pragma unroll
            for (int kk = 0; kk < 16; ++kk) {
                float av[4], bv[4];
                #pragma unroll
                for (int i = 0; i < 4; ++i) av[i] = As[(ty * 4 + i) * 17 + kk];
                #pragma unroll
                for (int j = 0; j < 4; ++j) bv[j] = Bs[(tx * 4 + j) * 17 + kk];
                #pragma unroll
                for (int i = 0; i < 4; ++i)
                    #pragma unroll
                    for (int j = 0; j < 4; ++j)
                        acc[i][j] += av[i] * bv[j];
            }
            __syncthreads();
        }
        #pragma unroll
        for (int j = 0; j < 4; ++j) {
            const int b = b0 + tx * 4 + j;
            float4 col = make_float4(acc[0][j], acc[1][j], acc[2][j], acc[3][j]);
            *(float4*)(Gp + ((size_t)kch * 512 + b) * 512 + a0 + ty * 4) = col;
        }
    } else {
        // ---- split_v: Bt[512+n][k] = hi(V[k][n]) ----
        float* tile = smem;            // [64][65]
        const int z = blk - 512;
        const int k0 = (z & 7) * 64;
        const int n0 = (z >> 3) * 64;
        #pragma unroll
        for (int rr = 0; rr < 4; ++rr) {
            const int row = (tid >> 4) * 4 + rr;
            const int col = (tid & 15) * 4;
            const float4 w = *(const float4*)(Vw + (size_t)(k0 + row) * Dn + n0 + col);
            tile[row * 65 + col + 0] = w.x; tile[row * 65 + col + 1] = w.y;
            tile[row * 65 + col + 2] = w.z; tile[row * 65 + col + 3] = w.w;
        }
        __syncthreads();
        const int n  = tid >> 2;
        const int ks = (tid & 3) * 16;
        union { bs8 v; unsigned short u[8]; } hi0, hi1;
        #pragma unroll
        for (int i = 0; i < 8; ++i) {
            hi0.u[i] = f2bf(tile[(ks + i) * 65 + n]);
            hi1.u[i] = f2bf(tile[(ks + 8 + i) * 65 + n]);
        }
        short* base = Bt + (size_t)(512 + n0 + n) * 1024 + k0 + ks;
        *(bs8*)base       = hi0.v;
        *(bs8*)(base + 8) = hi1.v;
    }
}

// ---------------------------------------------------------------------------
// Kernel 2: pack G = sum of 8 partials, split hi/lo into Bt rows [0,512):
// Bt[b][a] = hi(G[a][b]), Bt[b][512+a] = lo.
// ---------------------------------------------------------------------------
__global__ __launch_bounds__(256) void pack_g(const float* __restrict__ Gp,
                                              short* __restrict__ Bt)
{
    const int i = blockIdx.x * 256 + threadIdx.x;   // 32768 threads
    const int b = i >> 6;
    const int a8 = (i & 63) * 8;
    float s[8] = {};
    #pragma unroll
    for (int kc = 0; kc < 8; ++kc) {
        const float* p = Gp + ((size_t)kc * 512 + b) * 512 + a8;
        const float4 p0 = *(const float4*)p;
        const float4 p1 = *(const float4*)(p + 4);
        s[0] += p0.x; s[1] += p0.y; s[2] += p0.z; s[3] += p0.w;
        s[4] += p1.x; s[5] += p1.y; s[6] += p1.z; s[7] += p1.w;
    }
    union { bs8 v; unsigned short u[8]; } hi, lo;
    #pragma unroll
    for (int j = 0; j < 8; ++j) {
        const unsigned short h = f2bf(s[j]);
        hi.u[j] = h;
        lo.u[j] = f2bf(s[j] - bf2f(h));
    }
    short* base = Bt + (size_t)b * 1024 + a8;
    *(bs8*)base         = hi.v;
    *(bs8*)(base + 512) = lo.v;
}

// ---------------------------------------------------------------------------
// Kernel 3: bf16 MFMA GEMM, reg-staged f32 A, single-barrier dbuf (loads
// issued BEFORE compute, so the barrier drain is covered by compute).
//   Y (blocks 0..255):  K=512, 3 terms/chunk -> Yh/Yl bf16 planes
//   V (blocks 256..511): K=512, hi term     -> Vt transposed bf16 [512][8192]
// 128x128 tile; 8 waves as 2(wr) x 4(wc), each 64x32 (acc[4][2]).
// ---------------------------------------------------------------------------
__global__ __launch_bounds__(512, 4) void gemm_mfma(
    const float* __restrict__ X, const short* __restrict__ Bt,
    short* __restrict__ Yh, short* __restrict__ Yl, short* __restrict__ Vt)
{
    // [buf][plane]: 0=Ahi 1=Alo 2=B0(Ghi/Vhi) 3=B1(Glo); 8KB planes, 64KB total
    __shared__ short lds[2][4][128 * 32];

    const int lin = blockIdx.x;              // 0..511
    const int xcd = lin & 7;
    const int s   = lin >> 3;                // 0..63
    int mt, nt;
    if (s < 32) {                            // Y blocks first
        mt = xcd * 8 + (s & 7);
        nt = s >> 3;                         // 0..3
    } else {
        const int v = s - 32;
        mt = xcd * 8 + (v & 7);
        nt = 4 + (v >> 3);                   // 4..7
    }
    const int m0 = mt * 128, n0g = nt * 128;
    const int slab = nt >> 2;                // 0=Y, 1=V

    const int tid = threadIdx.x;
    const int ln  = tid & 63;
    const int wid = tid >> 6;                // 0..7
    const int wr = wid >> 2, wc = wid & 3;   // 2 x 4 waves
    const int lrow = ln & 15;
    const int lkb  = ln >> 4;                // 0..3

    fx4 acc[4][2] = {};

    // A staging geometry: thread -> (row, 8-elem chunk)
    const int ar = tid >> 2;                 // 0..127
    const int aj = tid & 3;                  // chunk 0..3
    const int aoff = ar * 32 + (aj ^ fsw(ar)) * 8;   // swizzled LDS offset
    const float* xrow = X + (size_t)(m0 + ar) * 512 + aj * 8;

    // B staging geometry (pre-swizzled global source, linear LDS dest)
    const int bnr = tid >> 2, bjj = tid & 3;
    const int bjs = bjj ^ fsw(bnr);
    const size_t bsrc = (size_t)(n0g + bnr) * 1024 + bjs * 8;

    auto stageB = [&](int bi, int k0) {
        __builtin_amdgcn_global_load_lds(
            (const __attribute__((address_space(1))) unsigned int*)(Bt + bsrc + k0),
            (__attribute__((address_space(3))) unsigned int*)(&lds[bi][2][tid * 8]), 16, 0, 0);
        if (slab == 0)
            __builtin_amdgcn_global_load_lds(
                (const __attribute__((address_space(1))) unsigned int*)(Bt + bsrc + 512 + k0),
                (__attribute__((address_space(3))) unsigned int*)(&lds[bi][3][tid * 8]), 16, 0, 0);
    };
    auto writeA = [&](int bi, const float4& f0, const float4& f1) {
        const float xs[8] = {f0.x, f0.y, f0.z, f0.w, f1.x, f1.y, f1.z, f1.w};
        union { bs8 v; unsigned short u[8]; } hi, lo;
        #pragma unroll
        for (int e = 0; e < 8; ++e) {
            const unsigned short h = f2bf(xs[e]);
            hi.u[e] = h;
            lo.u[e] = f2bf(xs[e] - bf2f(h));
        }
        *(bs8*)(&lds[bi][0][aoff]) = hi.v;
        if (slab == 0) *(bs8*)(&lds[bi][1][aoff]) = lo.v;
    };
    auto compute = [&](int bi) {
        bs8 ah[4], al[4], b0[2], b1[2];
        #pragma unroll
        for (int mf = 0; mf < 4; ++mf) {
            const int m = wr * 64 + mf * 16 + lrow;
            const int off = m * 32 + ((lkb ^ fsw(m)) * 8);
            ah[mf] = *(const bs8*)(&lds[bi][0][off]);
            if (slab == 0) al[mf] = *(const bs8*)(&lds[bi][1][off]);
        }
        #pragma unroll
        for (int nf = 0; nf < 2; ++nf) {
            const int n = wc * 32 + nf * 16 + lrow;
            const int off = n * 32 + ((lkb ^ fsw(n)) * 8);
            b0[nf] = *(const bs8*)(&lds[bi][2][off]);
            if (slab == 0) b1[nf] = *(const bs8*)(&lds[bi][3][off]);
        }
        #pragma unroll
        for (int mf = 0; mf < 4; ++mf)
            #pragma unroll
            for (int nf = 0; nf < 2; ++nf) {
                acc[mf][nf] = __builtin_amdgcn_mfma_f32_16x16x32_bf16(
                    ah[mf], b0[nf], acc[mf][nf], 0, 0, 0);
                if (slab == 0) {
                    acc[mf][nf] = __builtin_amdgcn_mfma_f32_16x16x32_bf16(
                        al[mf], b0[nf], acc[mf][nf], 0, 0, 0);
                    acc[mf][nf] = __builtin_amdgcn_mfma_f32_16x16x32_bf16(
                        ah[mf], b1[nf], acc[mf][nf], 0, 0, 0);
                }
            }
    };

    // prologue: chunk 0 into buf 0
    {
        const float4 f0 = *(const float4*)xrow;
        const float4 f1 = *(const float4*)(xrow + 4);
        stageB(0, 0);
        writeA(0, f0, f1);
    }
    __syncthreads();

    for (int it = 0; it < 16; ++it) {
        const int bi = it & 1;
        float4 n0, n1;
        if (it < 15) {
            const float* p = xrow + (it + 1) * 32;
            n0 = *(const float4*)p;
            n1 = *(const float4*)(p + 4);
            stageB(bi ^ 1, (it + 1) * 32);
        }
        compute(bi);
        if (it < 15) writeA(bi ^ 1, n0, n1);
        __syncthreads();
    }

    if (slab == 0) {
        // Y epilogue: split into Yh/Yl bf16 planes
        #pragma unroll
        for (int mf = 0; mf < 4; ++mf) {
            #pragma unroll
            for (int nf = 0; nf < 2; ++nf) {
                const int col = n0g + wc * 32 + nf * 16 + lrow;
                #pragma unroll
                for (int r = 0; r < 4; ++r) {
                    const int row = m0 + wr * 64 + mf * 16 + lkb * 4 + r;
                    const float v = acc[mf][nf][r];
                    const unsigned short h = f2bf(v);
                    Yh[(size_t)row * 512 + col] = (short)h;
                    Yl[(size_t)row * 512 + col] = (short)f2bf(v - bf2f(h));
                }
            }
        }
    } else {
        // V epilogue: transposed store Vt[d][token], 4 rows -> one 8B store
        #pragma unroll
        for (int mf = 0; mf < 4; ++mf) {
            #pragma unroll
            for (int nf = 0; nf < 2; ++nf) {
                const int c = (n0g - 512) + wc * 32 + nf * 16 + lrow;   // d
                const int row0 = m0 + wr * 64 + mf * 16 + lkb * 4;
                sh4 v4;
                #pragma unroll
                for (int r = 0; r < 4; ++r) v4[r] = (short)f2bf(acc[mf][nf][r]);
                *(sh4*)(Vt + (size_t)c * 8192 + row0) = v4;
            }
        }
    }
}

// ---------------------------------------------------------------------------
// Kernel 4: banded attention via MFMA. One wave per 16-token strip.
//   S[i][j] = Y[t0+i] . X[t0-15+j]; Y = Yh+Yl planes, X split in-lane from
//   exact f32 (HW cvt). Vt B-fragments gathered into registers BEFORE the QK
//   phase (independent loads; latency hidden under QK compute).
//   Band: src<0 slots -> logit 0 exactly (exp(0) in denominator), no V term.
// ---------------------------------------------------------------------------
__global__ __launch_bounds__(64, 1) void attn_mfma(
    const float* __restrict__ X,
    const short* __restrict__ Yh, const short* __restrict__ Yl,
    const short* __restrict__ Vt, float* __restrict__ out)
{
    __shared__ short Plds[16 * 32];

    const int lin = blockIdx.x;                   // 0..511
    const int strip = (lin & 7) * 64 + (lin >> 3);  // XCD swizzle (512=8x64)
    const int t0 = strip * 16;
    const int bat = t0 >> 10;
    const int tt0 = t0 & 1023;
    const int l  = threadIdx.x;                   // 0..63
    const int lr = l & 15;
    const int lg = l >> 4;                        // 0..3

    // ---- hoisted PV B-fragments (OOB reads hit finite ws bytes only where
    //      P=0) ----
    const long svt = (long)bat * 1024 + (tt0 - 15 + lg * 8);
    bs8 bv[32];
    #pragma unroll
    for (int nf = 0; nf < 32; ++nf)
        bv[nf] = *(const bs8*)(Vt + (long)(nf * 16 + lr) * 8192 + svt);

    const size_t yrow = (size_t)(t0 + lr) * 512 + lg * 8;
    const int srcl0 = tt0 - 15 + lr;              // local src for j=lr
    const int srcl1 = tt0 + 1 + lr;               // local src for j=lr+16
    const int r0c = srcl0 < 0 ? 0 : srcl0;
    const int r1c = srcl1 > 1023 ? 1023 : srcl1;  // only j=31 (masked) hits 1024
    const size_t xrow0 = ((size_t)(bat * 1024 + r0c)) * 512 + lg * 8;
    const size_t xrow1 = ((size_t)(bat * 1024 + r1c)) * 512 + lg * 8;

    fx4 s0a = {0,0,0,0}, s0b = {0,0,0,0};
    fx4 s1a = {0,0,0,0}, s1b = {0,0,0,0};
    #pragma unroll
    for (int k0 = 0; k0 < 512; k0 += 32) {
        const bs8 ah = *(const bs8*)(Yh + yrow + k0);
        const bs8 al = *(const bs8*)(Yl + yrow + k0);
        const float4 p0a = *(const float4*)(X + xrow0 + k0);
        const float4 p0b = *(const float4*)(X + xrow0 + k0 + 4);
        const float4 p1a = *(const float4*)(X + xrow1 + k0);
        const float4 p1b = *(const float4*)(X + xrow1 + k0 + 4);
        const float x0s[8] = {p0a.x,p0a.y,p0a.z,p0a.w,p0b.x,p0b.y,p0b.z,p0b.w};
        const float x1s[8] = {p1a.x,p1a.y,p1a.z,p1a.w,p1b.x,p1b.y,p1b.z,p1b.w};
        union { bs8 v; unsigned short u[8]; } bh0, bl0, bh1, bl1;
        #pragma unroll
        for (int e = 0; e < 8; ++e) {
            unsigned short h = f2bf(x0s[e]);
            bh0.u[e] = h; bl0.u[e] = f2bf(x0s[e] - bf2f(h));
            h = f2bf(x1s[e]);
            bh1.u[e] = h; bl1.u[e] = f2bf(x1s[e] - bf2f(h));
        }
        s0a = __builtin_amdgcn_mfma_f32_16x16x32_bf16(ah, bh0.v, s0a, 0, 0, 0);
        s0b = __builtin_amdgcn_mfma_f32_16x16x32_bf16(al, bh0.v, s0b, 0, 0, 0);
        s0b = __builtin_amdgcn_mfma_f32_16x16x32_bf16(ah, bl0.v, s0b, 0, 0, 0);
        s1a = __builtin_amdgcn_mfma_f32_16x16x32_bf16(ah, bh1.v, s1a, 0, 0, 0);
        s1b = __builtin_amdgcn_mfma_f32_16x16x32_bf16(al, bh1.v, s1b, 0, 0, 0);
        s1b = __builtin_amdgcn_mfma_f32_16x16x32_bf16(ah, bl1.v, s1b, 0, 0, 0);

        // concat copy: rows t0..t0+15 from the same loads (exact f32)
        if (lr == 15) {               // xrow0 == row t0
            float* o = out + (size_t)t0 * 1024 + k0 + lg * 8;
            *(float4*)o       = p0a;
            *(float4*)(o + 4) = p0b;
        } else {                      // xrow1 == row t0+1+lr  (lr<15)
            float* o = out + (size_t)(t0 + 1 + lr) * 1024 + k0 + lg * 8;
            *(float4*)o       = p1a;
            *(float4*)(o + 4) = p1b;
        }
    }

    // ---- band mask + softmax (per lane: 4 rows x 2 cols) ----
    #pragma unroll
    for (int r = 0; r < 4; ++r) {
        const int i = lg * 4 + r;
        const int d0 = lr - i;            // w-offset for j=lr
        const int d1 = lr + 16 - i;       // w-offset for j=lr+16
        const bool in0 = (d0 >= 0) && (d0 <= 15);
        const bool in1 = (d1 >= 0) && (d1 <= 15);
        const bool z0 = srcl0 < 0;        // src<0 -> logit 0 exactly
        float v0 = z0 ? 0.0f : (s0a[r] + s0b[r]);
        float v1 = s1a[r] + s1b[r];
        v0 = in0 ? v0 : -3.0e38f;
        v1 = in1 ? v1 : -3.0e38f;
        float m = fmaxf(v0, v1);
        #pragma unroll
        for (int st = 1; st < 16; st <<= 1) m = fmaxf(m, __shfl_xor(m, st, 64));
        const float e0 = in0 ? __expf(v0 - m) : 0.0f;
        const float e1 = in1 ? __expf(v1 - m) : 0.0f;
        float den = e0 + e1;
        #pragma unroll
        for (int st = 1; st < 16; st <<= 1) den += __shfl_xor(den, st, 64);
        const float inv = 1.0f / den;
        const float p0 = (in0 && !z0) ? e0 * inv : 0.0f;
        const float p1 = in1 ? e1 * inv : 0.0f;
        Plds[i * 32 + lr]      = (short)f2bf(p0);
        Plds[i * 32 + lr + 16] = (short)f2bf(p1);
    }
    __syncthreads();

    // ---- PV: answer(16x512) = P(16x32) @ V'_window(32x512), B pre-loaded ----
    const bs8 pa = *(const bs8*)(Plds + lr * 32 + lg * 8);
    #pragma unroll
    for (int nf = 0; nf < 32; ++nf) {
        const int d = nf * 16 + lr;
        fx4 c = {0, 0, 0, 0};
        c = __builtin_amdgcn_mfma_f32_16x16x32_bf16(pa, bv[nf], c, 0, 0, 0);
        #pragma unroll
        for (int r = 0; r < 4; ++r)
            out[(size_t)(t0 + lg * 4 + r) * 1024 + 512 + d] = c[r];
    }
}

// ---------------------------------------------------------------------------
extern "C" void kernel_launch(void* const* d_in, const int* in_sizes, int n_in,
                              void* d_out, int out_size, void* d_ws, size_t ws_size,
                              hipStream_t stream)
{
    const float* X  = (const float*)d_in[0];
    const float* Mw = (const float*)d_in[1];
    const float* Cw = (const float*)d_in[2];
    const float* Vw = (const float*)d_in[3];
    float* out = (float*)d_out;

    // ws layout (34 MB total), Vt LAST (OOB guard reads land in Yl):
    short* Bt = (short*)d_ws;                                   // 2 MB
    float* Gp = (float*)(Bt + (size_t)1024 * 1024);             // 8 MB
    short* Yh = (short*)(Gp + (size_t)8 * 512 * 512);           // 8 MB
    short* Yl = Yh + (size_t)BT * 512;                          // 8 MB
    short* Vt = Yl + (size_t)BT * 512;                          // 8 MB

    wprep<<<576, 256, 0, stream>>>(Mw, Cw, Vw, Gp, Bt);
    pack_g<<<128, 256, 0, stream>>>(Gp, Bt);
    gemm_mfma<<<512, 512, 0, stream>>>(X, Bt, Yh, Yl, Vt);
    attn_mfma<<<512, 64, 0, stream>>>(X, Yh, Yl, Vt, out);
}

// Round 16
// 62.823 us; speedup vs baseline: 2.0391x; 1.0327x over previous
//
#include <hip/hip_runtime.h>
#include <hip/hip_bf16.h>
#include <math.h>

// Problem constants (B=8, T=1024, D=512, LEFT=16, RIGHT=0)
constexpr int Tn = 1024;
constexpr int Dn = 512;
constexpr int BT = 8192;
constexpr int WIN = 16;

typedef short bs8 __attribute__((ext_vector_type(8)));     // 8 bf16 (bit pattern)
typedef short sh4 __attribute__((ext_vector_type(4)));     // 4 bf16 (8 B)
typedef unsigned short us8 __attribute__((ext_vector_type(8)));
typedef float fx4 __attribute__((ext_vector_type(4)));

// bf16 helpers: HW conversion (v_cvt_pk_bf16_f32 via compiler), RNE
__device__ inline unsigned short f2bf(float f) {
    union { __hip_bfloat16 b; unsigned short u; } c;
    c.b = __float2bfloat16(f);
    return c.u;
}
__device__ inline float bf2f(unsigned short h) {
    return __uint_as_float(((unsigned int)h) << 16);
}
// chunk-swizzle involution: spreads ds_read banks (bijective per 4-chunk row)
__device__ inline int fsw(int m) { return (m & 3) ^ ((m >> 2) & 3); }

// ---------------------------------------------------------------------------
// Kernel 1 (wprep):
//   [0,512):   split-K(8) partials of G = M @ C^T (K-chunk 64)
//   [512,576): split+transpose V (hi) -> Bt rows [512,1024)
// ---------------------------------------------------------------------------
__global__ __launch_bounds__(256) void wprep(
    const float* __restrict__ Mw, const float* __restrict__ Cw,
    const float* __restrict__ Vw,
    float* __restrict__ Gp, short* __restrict__ Bt)
{
    __shared__ float smem[64 * 65];
    const int blk = blockIdx.x;
    const int tid = threadIdx.x;

    if (blk < 512) {
        // ---- g_partial: Gp[kc][b][a] = sum_{j in 64-chunk} M[a,j] C[b,j] ----
        float* As = smem;              // [64][17]
        float* Bs = smem + 64 * 17;
        const int kch = blk >> 6;           // 0..7
        const int r6 = blk & 63;
        const int b0 = (r6 & 7) * 64;
        const int a0 = (r6 >> 3) * 64;
        const int tx = tid & 15, ty = tid >> 4;

        float acc[4][4] = {};
        for (int j0 = kch * 64; j0 < kch * 64 + 64; j0 += 16) {
            const int r = tid >> 2;
            const int c = (tid & 3) * 4;
            const float4 a = *(const float4*)(Mw + (size_t)(a0 + r) * Dn + j0 + c);
            As[r * 17 + c + 0] = a.x; As[r * 17 + c + 1] = a.y;
            As[r * 17 + c + 2] = a.z; As[r * 17 + c + 3] = a.w;
            const float4 b = *(const float4*)(Cw + (size_t)(b0 + r) * Dn + j0 + c);
            Bs[r * 17 + c + 0] = b.x; Bs[r * 17 + c + 1] = b.y;
            Bs[r * 17 + c + 2] = b.z; Bs[r * 17 + c + 3] = b.w;
            __syncthreads();
            #pragma unroll
            for (int kk = 0; kk < 16; ++kk) {
                float av[4], bv[4];
                #pragma unroll
                for (int i = 0; i < 4; ++i) av[i] = As[(ty * 4 + i) * 17 + kk];
                #pragma unroll
                for (int j = 0; j < 4; ++j) bv[j] = Bs[(tx * 4 + j) * 17 + kk];
                #pragma unroll
                for (int i = 0; i < 4; ++i)
                    #pragma unroll
                    for (int j = 0; j < 4; ++j)
                        acc[i][j] += av[i] * bv[j];
            }
            __syncthreads();
        }
        #pragma unroll
        for (int j = 0; j < 4; ++j) {
            const int b = b0 + tx * 4 + j;
            float4 col = make_float4(acc[0][j], acc[1][j], acc[2][j], acc[3][j]);
            *(float4*)(Gp + ((size_t)kch * 512 + b) * 512 + a0 + ty * 4) = col;
        }
    } else {
        // ---- split_v: Bt[512+n][k] = hi(V[k][n]) ----
        float* tile = smem;            // [64][65]
        const int z = blk - 512;
        const int k0 = (z & 7) * 64;
        const int n0 = (z >> 3) * 64;
        #pragma unroll
        for (int rr = 0; rr < 4; ++rr) {
            const int row = (tid >> 4) * 4 + rr;
            const int col = (tid & 15) * 4;
            const float4 w = *(const float4*)(Vw + (size_t)(k0 + row) * Dn + n0 + col);
            tile[row * 65 + col + 0] = w.x; tile[row * 65 + col + 1] = w.y;
            tile[row * 65 + col + 2] = w.z; tile[row * 65 + col + 3] = w.w;
        }
        __syncthreads();
        const int n  = tid >> 2;
        const int ks = (tid & 3) * 16;
        union { bs8 v; unsigned short u[8]; } hi0, hi1;
        #pragma unroll
        for (int i = 0; i < 8; ++i) {
            hi0.u[i] = f2bf(tile[(ks + i) * 65 + n]);
            hi1.u[i] = f2bf(tile[(ks + 8 + i) * 65 + n]);
        }
        short* base = Bt + (size_t)(512 + n0 + n) * 1024 + k0 + ks;
        *(bs8*)base       = hi0.v;
        *(bs8*)(base + 8) = hi1.v;
    }
}

// ---------------------------------------------------------------------------
// Kernel 2: pack G = sum of 8 partials, split hi/lo into Bt rows [0,512):
// Bt[b][a] = hi(G[a][b]), Bt[b][512+a] = lo.
// ---------------------------------------------------------------------------
__global__ __launch_bounds__(256) void pack_g(const float* __restrict__ Gp,
                                              short* __restrict__ Bt)
{
    const int i = blockIdx.x * 256 + threadIdx.x;   // 32768 threads
    const int b = i >> 6;
    const int a8 = (i & 63) * 8;
    float s[8] = {};
    #pragma unroll
    for (int kc = 0; kc < 8; ++kc) {
        const float* p = Gp + ((size_t)kc * 512 + b) * 512 + a8;
        const float4 p0 = *(const float4*)p;
        const float4 p1 = *(const float4*)(p + 4);
        s[0] += p0.x; s[1] += p0.y; s[2] += p0.z; s[3] += p0.w;
        s[4] += p1.x; s[5] += p1.y; s[6] += p1.z; s[7] += p1.w;
    }
    union { bs8 v; unsigned short u[8]; } hi, lo;
    #pragma unroll
    for (int j = 0; j < 8; ++j) {
        const unsigned short h = f2bf(s[j]);
        hi.u[j] = h;
        lo.u[j] = f2bf(s[j] - bf2f(h));
    }
    short* base = Bt + (size_t)b * 1024 + a8;
    *(bs8*)base         = hi.v;
    *(bs8*)(base + 512) = lo.v;
}

// ---------------------------------------------------------------------------
// Kernel 3: bf16 MFMA GEMM, reg-staged f32 A, single-barrier dbuf (loads
// issued BEFORE compute, so the barrier drain is covered by compute).
//   Y (blocks 0..255):  K=512, 3 terms/chunk -> Yh/Yl bf16 planes
//   V (blocks 256..511): K=512, hi term     -> Vt transposed bf16 [512][8192]
// 128x128 tile; 8 waves as 2(wr) x 4(wc), each 64x32 (acc[4][2]).
// ---------------------------------------------------------------------------
__global__ __launch_bounds__(512, 4) void gemm_mfma(
    const float* __restrict__ X, const short* __restrict__ Bt,
    short* __restrict__ Yh, short* __restrict__ Yl, short* __restrict__ Vt)
{
    // [buf][plane]: 0=Ahi 1=Alo 2=B0(Ghi/Vhi) 3=B1(Glo); 8KB planes, 64KB total
    __shared__ short lds[2][4][128 * 32];

    const int lin = blockIdx.x;              // 0..511
    const int xcd = lin & 7;
    const int s   = lin >> 3;                // 0..63
    int mt, nt;
    if (s < 32) {                            // Y blocks first
        mt = xcd * 8 + (s & 7);
        nt = s >> 3;                         // 0..3
    } else {
        const int v = s - 32;
        mt = xcd * 8 + (v & 7);
        nt = 4 + (v >> 3);                   // 4..7
    }
    const int m0 = mt * 128, n0g = nt * 128;
    const int slab = nt >> 2;                // 0=Y, 1=V

    const int tid = threadIdx.x;
    const int ln  = tid & 63;
    const int wid = tid >> 6;                // 0..7
    const int wr = wid >> 2, wc = wid & 3;   // 2 x 4 waves
    const int lrow = ln & 15;
    const int lkb  = ln >> 4;                // 0..3

    fx4 acc[4][2] = {};

    // A staging geometry: thread -> (row, 8-elem chunk)
    const int ar = tid >> 2;                 // 0..127
    const int aj = tid & 3;                  // chunk 0..3
    const int aoff = ar * 32 + (aj ^ fsw(ar)) * 8;   // swizzled LDS offset
    const float* xrow = X + (size_t)(m0 + ar) * 512 + aj * 8;

    // B staging geometry (pre-swizzled global source, linear LDS dest)
    const int bnr = tid >> 2, bjj = tid & 3;
    const int bjs = bjj ^ fsw(bnr);
    const size_t bsrc = (size_t)(n0g + bnr) * 1024 + bjs * 8;

    auto stageB = [&](int bi, int k0) {
        __builtin_amdgcn_global_load_lds(
            (const __attribute__((address_space(1))) unsigned int*)(Bt + bsrc + k0),
            (__attribute__((address_space(3))) unsigned int*)(&lds[bi][2][tid * 8]), 16, 0, 0);
        if (slab == 0)
            __builtin_amdgcn_global_load_lds(
                (const __attribute__((address_space(1))) unsigned int*)(Bt + bsrc + 512 + k0),
                (__attribute__((address_space(3))) unsigned int*)(&lds[bi][3][tid * 8]), 16, 0, 0);
    };
    auto writeA = [&](int bi, const float4& f0, const float4& f1) {
        const float xs[8] = {f0.x, f0.y, f0.z, f0.w, f1.x, f1.y, f1.z, f1.w};
        union { bs8 v; unsigned short u[8]; } hi, lo;
        #pragma unroll
        for (int e = 0; e < 8; ++e) {
            const unsigned short h = f2bf(xs[e]);
            hi.u[e] = h;
            lo.u[e] = f2bf(xs[e] - bf2f(h));
        }
        *(bs8*)(&lds[bi][0][aoff]) = hi.v;
        if (slab == 0) *(bs8*)(&lds[bi][1][aoff]) = lo.v;
    };
    auto compute = [&](int bi) {
        bs8 ah[4], al[4], b0[2], b1[2];
        #pragma unroll
        for (int mf = 0; mf < 4; ++mf) {
            const int m = wr * 64 + mf * 16 + lrow;
            const int off = m * 32 + ((lkb ^ fsw(m)) * 8);
            ah[mf] = *(const bs8*)(&lds[bi][0][off]);
            if (slab == 0) al[mf] = *(const bs8*)(&lds[bi][1][off]);
        }
        #pragma unroll
        for (int nf = 0; nf < 2; ++nf) {
            const int n = wc * 32 + nf * 16 + lrow;
            const int off = n * 32 + ((lkb ^ fsw(n)) * 8);
            b0[nf] = *(const bs8*)(&lds[bi][2][off]);
            if (slab == 0) b1[nf] = *(const bs8*)(&lds[bi][3][off]);
        }
        #pragma unroll
        for (int mf = 0; mf < 4; ++mf)
            #pragma unroll
            for (int nf = 0; nf < 2; ++nf) {
                acc[mf][nf] = __builtin_amdgcn_mfma_f32_16x16x32_bf16(
                    ah[mf], b0[nf], acc[mf][nf], 0, 0, 0);
                if (slab == 0) {
                    acc[mf][nf] = __builtin_amdgcn_mfma_f32_16x16x32_bf16(
                        al[mf], b0[nf], acc[mf][nf], 0, 0, 0);
                    acc[mf][nf] = __builtin_amdgcn_mfma_f32_16x16x32_bf16(
                        ah[mf], b1[nf], acc[mf][nf], 0, 0, 0);
                }
            }
    };

    // prologue: chunk 0 into buf 0
    {
        const float4 f0 = *(const float4*)xrow;
        const float4 f1 = *(const float4*)(xrow + 4);
        stageB(0, 0);
        writeA(0, f0, f1);
    }
    __syncthreads();

    for (int it = 0; it < 16; ++it) {
        const int bi = it & 1;
        float4 n0, n1;
        if (it < 15) {
            const float* p = xrow + (it + 1) * 32;
            n0 = *(const float4*)p;
            n1 = *(const float4*)(p + 4);
            stageB(bi ^ 1, (it + 1) * 32);
        }
        compute(bi);
        if (it < 15) writeA(bi ^ 1, n0, n1);
        __syncthreads();
    }

    if (slab == 0) {
        // Y epilogue: split into Yh/Yl bf16 planes
        #pragma unroll
        for (int mf = 0; mf < 4; ++mf) {
            #pragma unroll
            for (int nf = 0; nf < 2; ++nf) {
                const int col = n0g + wc * 32 + nf * 16 + lrow;
                #pragma unroll
                for (int r = 0; r < 4; ++r) {
                    const int row = m0 + wr * 64 + mf * 16 + lkb * 4 + r;
                    const float v = acc[mf][nf][r];
                    const unsigned short h = f2bf(v);
                    Yh[(size_t)row * 512 + col] = (short)h;
                    Yl[(size_t)row * 512 + col] = (short)f2bf(v - bf2f(h));
                }
            }
        }
    } else {
        // V epilogue: transposed store Vt[d][token], 4 rows -> one 8B store
        #pragma unroll
        for (int mf = 0; mf < 4; ++mf) {
            #pragma unroll
            for (int nf = 0; nf < 2; ++nf) {
                const int c = (n0g - 512) + wc * 32 + nf * 16 + lrow;   // d
                const int row0 = m0 + wr * 64 + mf * 16 + lkb * 4;
                sh4 v4;
                #pragma unroll
                for (int r = 0; r < 4; ++r) v4[r] = (short)f2bf(acc[mf][nf][r]);
                *(sh4*)(Vt + (size_t)c * 8192 + row0) = v4;
            }
        }
    }
}

// ---------------------------------------------------------------------------
// Kernel 4: banded attention via MFMA — 4 cooperative waves per 16-token
// strip (8 waves/CU vs 1-wave version's 2: latency hiding).
//   QK: wave w computes K-chunks [4w,4w+4) -> partial S; f32 LDS reduce
//       (padded stride 20 to spread banks; deterministic order).
//   softmax: wave 0 computes + writes Plds (others idle at barrier).
//   PV: wave w owns d-columns [128w,128w+128); its 8 Vt fragments hoisted
//       at kernel entry (parallel issue across waves).
//   concat copy: each wave copies its own K-chunks' X rows (full coverage).
//   Band: src<0 slots -> logit 0 exactly (exp(0) in denominator), no V term.
// ---------------------------------------------------------------------------
__global__ __launch_bounds__(256, 1) void attn_mfma(
    const float* __restrict__ X,
    const short* __restrict__ Yh, const short* __restrict__ Yl,
    const short* __restrict__ Vt, float* __restrict__ out)
{
    __shared__ float Sred[4][64][20];   // 20KB, stride-20 pad (16B-aligned)
    __shared__ short Plds[16 * 32];

    const int lin = blockIdx.x;                   // 0..511
    const int strip = (lin & 7) * 64 + (lin >> 3);  // XCD swizzle (512=8x64)
    const int t0 = strip * 16;
    const int bat = t0 >> 10;
    const int tt0 = t0 & 1023;
    const int tid = threadIdx.x;
    const int l  = tid & 63;
    const int w  = tid >> 6;                      // wave 0..3
    const int lr = l & 15;
    const int lg = l >> 4;                        // 0..3

    // ---- hoisted PV B-fragments: wave w covers nf = 8w..8w+8 (OOB reads
    //      hit finite ws bytes only where P=0) ----
    const long svt = (long)bat * 1024 + (tt0 - 15 + lg * 8);
    bs8 bv[8];
    #pragma unroll
    for (int q = 0; q < 8; ++q)
        bv[q] = *(const bs8*)(Vt + (long)((w * 8 + q) * 16 + lr) * 8192 + svt);

    const size_t yrow = (size_t)(t0 + lr) * 512 + lg * 8;
    const int srcl0 = tt0 - 15 + lr;              // local src for j=lr
    const int srcl1 = tt0 + 1 + lr;               // local src for j=lr+16
    const int r0c = srcl0 < 0 ? 0 : srcl0;
    const int r1c = srcl1 > 1023 ? 1023 : srcl1;  // only j=31 (masked) hits 1024
    const size_t xrow0 = ((size_t)(bat * 1024 + r0c)) * 512 + lg * 8;
    const size_t xrow1 = ((size_t)(bat * 1024 + r1c)) * 512 + lg * 8;

    fx4 s0a = {0,0,0,0}, s0b = {0,0,0,0};
    fx4 s1a = {0,0,0,0}, s1b = {0,0,0,0};
    #pragma unroll
    for (int kc = 0; kc < 4; ++kc) {
        const int k0 = (w * 4 + kc) * 32;         // this wave's K-chunks
        const bs8 ah = *(const bs8*)(Yh + yrow + k0);
        const bs8 al = *(const bs8*)(Yl + yrow + k0);
        const float4 p0a = *(const float4*)(X + xrow0 + k0);
        const float4 p0b = *(const float4*)(X + xrow0 + k0 + 4);
        const float4 p1a = *(const float4*)(X + xrow1 + k0);
        const float4 p1b = *(const float4*)(X + xrow1 + k0 + 4);
        const float x0s[8] = {p0a.x,p0a.y,p0a.z,p0a.w,p0b.x,p0b.y,p0b.z,p0b.w};
        const float x1s[8] = {p1a.x,p1a.y,p1a.z,p1a.w,p1b.x,p1b.y,p1b.z,p1b.w};
        union { bs8 v; unsigned short u[8]; } bh0, bl0, bh1, bl1;
        #pragma unroll
        for (int e = 0; e < 8; ++e) {
            unsigned short h = f2bf(x0s[e]);
            bh0.u[e] = h; bl0.u[e] = f2bf(x0s[e] - bf2f(h));
            h = f2bf(x1s[e]);
            bh1.u[e] = h; bl1.u[e] = f2bf(x1s[e] - bf2f(h));
        }
        s0a = __builtin_amdgcn_mfma_f32_16x16x32_bf16(ah, bh0.v, s0a, 0, 0, 0);
        s0b = __builtin_amdgcn_mfma_f32_16x16x32_bf16(al, bh0.v, s0b, 0, 0, 0);
        s0b = __builtin_amdgcn_mfma_f32_16x16x32_bf16(ah, bl0.v, s0b, 0, 0, 0);
        s1a = __builtin_amdgcn_mfma_f32_16x16x32_bf16(ah, bh1.v, s1a, 0, 0, 0);
        s1b = __builtin_amdgcn_mfma_f32_16x16x32_bf16(al, bh1.v, s1b, 0, 0, 0);
        s1b = __builtin_amdgcn_mfma_f32_16x16x32_bf16(ah, bl1.v, s1b, 0, 0, 0);

        // concat copy: rows t0..t0+15 from the same loads (exact f32)
        if (lr == 15) {               // xrow0 == row t0
            float* o = out + (size_t)t0 * 1024 + k0 + lg * 8;
            *(float4*)o       = p0a;
            *(float4*)(o + 4) = p0b;
        } else {                      // xrow1 == row t0+1+lr  (lr<15)
            float* o = out + (size_t)(t0 + 1 + lr) * 1024 + k0 + lg * 8;
            *(float4*)o       = p1a;
            *(float4*)(o + 4) = p1b;
        }
    }

    // ---- cross-wave S reduction via LDS (deterministic order) ----
    {
        float* sp = &Sred[w][l][0];
        *((fx4*)sp + 0) = s0a; *((fx4*)sp + 1) = s0b;
        *((fx4*)sp + 2) = s1a; *((fx4*)sp + 3) = s1b;
    }
    __syncthreads();
    if (w == 0) {
        #pragma unroll
        for (int ow = 1; ow < 4; ++ow) {
            const float* op = &Sred[ow][l][0];
            s0a += *((const fx4*)op + 0); s0b += *((const fx4*)op + 1);
            s1a += *((const fx4*)op + 2); s1b += *((const fx4*)op + 3);
        }
        // ---- band mask + softmax (per lane: 4 rows x 2 cols) ----
        #pragma unroll
        for (int r = 0; r < 4; ++r) {
            const int i = lg * 4 + r;
            const int d0 = lr - i;            // w-offset for j=lr
            const int d1 = lr + 16 - i;       // w-offset for j=lr+16
            const bool in0 = (d0 >= 0) && (d0 <= 15);
            const bool in1 = (d1 >= 0) && (d1 <= 15);
            const bool z0 = srcl0 < 0;        // src<0 -> logit 0 exactly
            float v0 = z0 ? 0.0f : (s0a[r] + s0b[r]);
            float v1 = s1a[r] + s1b[r];
            v0 = in0 ? v0 : -3.0e38f;
            v1 = in1 ? v1 : -3.0e38f;
            float m = fmaxf(v0, v1);
            #pragma unroll
            for (int st = 1; st < 16; st <<= 1) m = fmaxf(m, __shfl_xor(m, st, 64));
            const float e0 = in0 ? __expf(v0 - m) : 0.0f;
            const float e1 = in1 ? __expf(v1 - m) : 0.0f;
            float den = e0 + e1;
            #pragma unroll
            for (int st = 1; st < 16; st <<= 1) den += __shfl_xor(den, st, 64);
            const float inv = 1.0f / den;
            const float p0 = (in0 && !z0) ? e0 * inv : 0.0f;
            const float p1 = in1 ? e1 * inv : 0.0f;
            Plds[i * 32 + lr]      = (short)f2bf(p0);
            Plds[i * 32 + lr + 16] = (short)f2bf(p1);
        }
    }
    __syncthreads();

    // ---- PV: answer(16x512) = P(16x32) @ V'_window(32x512); wave w owns
    //      d-columns [128w, 128w+128), B pre-loaded ----
    const bs8 pa = *(const bs8*)(Plds + lr * 32 + lg * 8);
    #pragma unroll
    for (int q = 0; q < 8; ++q) {
        const int d = (w * 8 + q) * 16 + lr;
        fx4 c = {0, 0, 0, 0};
        c = __builtin_amdgcn_mfma_f32_16x16x32_bf16(pa, bv[q], c, 0, 0, 0);
        #pragma unroll
        for (int r = 0; r < 4; ++r)
            out[(size_t)(t0 + lg * 4 + r) * 1024 + 512 + d] = c[r];
    }
}

// ---------------------------------------------------------------------------
extern "C" void kernel_launch(void* const* d_in, const int* in_sizes, int n_in,
                              void* d_out, int out_size, void* d_ws, size_t ws_size,
                              hipStream_t stream)
{
    const float* X  = (const float*)d_in[0];
    const float* Mw = (const float*)d_in[1];
    const float* Cw = (const float*)d_in[2];
    const float* Vw = (const float*)d_in[3];
    float* out = (float*)d_out;

    // ws layout (34 MB total), Vt LAST (OOB guard reads land in Yl):
    short* Bt = (short*)d_ws;                                   // 2 MB
    float* Gp = (float*)(Bt + (size_t)1024 * 1024);             // 8 MB
    short* Yh = (short*)(Gp + (size_t)8 * 512 * 512);           // 8 MB
    short* Yl = Yh + (size_t)BT * 512;                          // 8 MB
    short* Vt = Yl + (size_t)BT * 512;                          // 8 MB

    wprep<<<576, 256, 0, stream>>>(Mw, Cw, Vw, Gp, Bt);
    pack_g<<<128, 256, 0, stream>>>(Gp, Bt);
    gemm_mfma<<<512, 512, 0, stream>>>(X, Bt, Yh, Yl, Vt);
    attn_mfma<<<512, 256, 0, stream>>>(X, Yh, Yl, Vt, out);
}

// Round 17
// 61.500 us; speedup vs baseline: 2.0829x; 1.0215x over previous
//
#include <hip/hip_runtime.h>
#include <hip/hip_bf16.h>
#include <math.h>

// Problem constants (B=8, T=1024, D=512, LEFT=16, RIGHT=0)
constexpr int Tn = 1024;
constexpr int Dn = 512;
constexpr int BT = 8192;
constexpr int WIN = 16;

typedef short bs8 __attribute__((ext_vector_type(8)));     // 8 bf16 (bit pattern)
typedef short sh4 __attribute__((ext_vector_type(4)));     // 4 bf16 (8 B)
typedef unsigned short us8 __attribute__((ext_vector_type(8)));
typedef float fx4 __attribute__((ext_vector_type(4)));

// bf16 helpers: HW conversion (v_cvt_pk_bf16_f32 via compiler), RNE
__device__ inline unsigned short f2bf(float f) {
    union { __hip_bfloat16 b; unsigned short u; } c;
    c.b = __float2bfloat16(f);
    return c.u;
}
__device__ inline float bf2f(unsigned short h) {
    return __uint_as_float(((unsigned int)h) << 16);
}
// chunk-swizzle involution: spreads ds_read banks (bijective per 4-chunk row)
__device__ inline int fsw(int m) { return (m & 3) ^ ((m >> 2) & 3); }

// ---------------------------------------------------------------------------
// Kernel 1 (wprep):
//   [0,512):   split-K(8) partials of G = M @ C^T (K-chunk 64)
//   [512,576): split+transpose V (hi) -> Bt rows [512,1024)
// ---------------------------------------------------------------------------
__global__ __launch_bounds__(256) void wprep(
    const float* __restrict__ Mw, const float* __restrict__ Cw,
    const float* __restrict__ Vw,
    float* __restrict__ Gp, short* __restrict__ Bt)
{
    __shared__ float smem[64 * 65];
    const int blk = blockIdx.x;
    const int tid = threadIdx.x;

    if (blk < 512) {
        // ---- g_partial: Gp[kc][b][a] = sum_{j in 64-chunk} M[a,j] C[b,j] ----
        float* As = smem;              // [64][17]
        float* Bs = smem + 64 * 17;
        const int kch = blk >> 6;           // 0..7
        const int r6 = blk & 63;
        const int b0 = (r6 & 7) * 64;
        const int a0 = (r6 >> 3) * 64;
        const int tx = tid & 15, ty = tid >> 4;

        float acc[4][4] = {};
        for (int j0 = kch * 64; j0 < kch * 64 + 64; j0 += 16) {
            const int r = tid >> 2;
            const int c = (tid & 3) * 4;
            const float4 a = *(const float4*)(Mw + (size_t)(a0 + r) * Dn + j0 + c);
            As[r * 17 + c + 0] = a.x; As[r * 17 + c + 1] = a.y;
            As[r * 17 + c + 2] = a.z; As[r * 17 + c + 3] = a.w;
            const float4 b = *(const float4*)(Cw + (size_t)(b0 + r) * Dn + j0 + c);
            Bs[r * 17 + c + 0] = b.x; Bs[r * 17 + c + 1] = b.y;
            Bs[r * 17 + c + 2] = b.z; Bs[r * 17 + c + 3] = b.w;
            __syncthreads();
            #pragma unroll
            for (int kk = 0; kk < 16; ++kk) {
                float av[4], bv[4];
                #pragma unroll
                for (int i = 0; i < 4; ++i) av[i] = As[(ty * 4 + i) * 17 + kk];
                #pragma unroll
                for (int j = 0; j < 4; ++j) bv[j] = Bs[(tx * 4 + j) * 17 + kk];
                #pragma unroll
                for (int i = 0; i < 4; ++i)
                    #pragma unroll
                    for (int j = 0; j < 4; ++j)
                        acc[i][j] += av[i] * bv[j];
            }
            __syncthreads();
        }
        #pragma unroll
        for (int j = 0; j < 4; ++j) {
            const int b = b0 + tx * 4 + j;
            float4 col = make_float4(acc[0][j], acc[1][j], acc[2][j], acc[3][j]);
            *(float4*)(Gp + ((size_t)kch * 512 + b) * 512 + a0 + ty * 4) = col;
        }
    } else {
        // ---- split_v: Bt[512+n][k] = hi(V[k][n]) ----
        float* tile = smem;            // [64][65]
        const int z = blk - 512;
        const int k0 = (z & 7) * 64;
        const int n0 = (z >> 3) * 64;
        #pragma unroll
        for (int rr = 0; rr < 4; ++rr) {
            const int row = (tid >> 4) * 4 + rr;
            const int col = (tid & 15) * 4;
            const float4 w = *(const float4*)(Vw + (size_t)(k0 + row) * Dn + n0 + col);
            tile[row * 65 + col + 0] = w.x; tile[row * 65 + col + 1] = w.y;
            tile[row * 65 + col + 2] = w.z; tile[row * 65 + col + 3] = w.w;
        }
        __syncthreads();
        const int n  = tid >> 2;
        const int ks = (tid & 3) * 16;
        union { bs8 v; unsigned short u[8]; } hi0, hi1;
        #pragma unroll
        for (int i = 0; i < 8; ++i) {
            hi0.u[i] = f2bf(tile[(ks + i) * 65 + n]);
            hi1.u[i] = f2bf(tile[(ks + 8 + i) * 65 + n]);
        }
        short* base = Bt + (size_t)(512 + n0 + n) * 1024 + k0 + ks;
        *(bs8*)base       = hi0.v;
        *(bs8*)(base + 8) = hi1.v;
    }
}

// ---------------------------------------------------------------------------
// Kernel 2: pack G = sum of 8 partials, split hi/lo into Bt rows [0,512):
// Bt[b][a] = hi(G[a][b]), Bt[b][512+a] = lo.
// 256 blocks (1/CU), 4 elements per thread (float4 chunk): latency-bound
// kernel widened from 128 blocks (0.5/CU).
// ---------------------------------------------------------------------------
__global__ __launch_bounds__(256) void pack_g(const float* __restrict__ Gp,
                                              short* __restrict__ Bt)
{
    const int i = blockIdx.x * 256 + threadIdx.x;   // 65536 threads
    const int b = i >> 7;            // 0..511
    const int a4 = (i & 127) * 4;    // 0..508
    float s[4] = {};
    #pragma unroll
    for (int kc = 0; kc < 8; ++kc) {
        const float4 p = *(const float4*)(Gp + ((size_t)kc * 512 + b) * 512 + a4);
        s[0] += p.x; s[1] += p.y; s[2] += p.z; s[3] += p.w;
    }
    sh4 h4, l4;
    #pragma unroll
    for (int j = 0; j < 4; ++j) {
        const unsigned short h = f2bf(s[j]);
        h4[j] = (short)h;
        l4[j] = (short)f2bf(s[j] - bf2f(h));
    }
    *(sh4*)(Bt + (size_t)b * 1024 + a4)       = h4;
    *(sh4*)(Bt + (size_t)b * 1024 + 512 + a4) = l4;
}

// ---------------------------------------------------------------------------
// Kernel 3: bf16 MFMA GEMM, reg-staged f32 A, single-barrier dbuf (loads
// issued BEFORE compute, so the barrier drain is covered by compute).
//   Y (blocks 0..255):  K=512, 3 terms/chunk -> Yh/Yl bf16 planes
//   V (blocks 256..511): K=512, hi term     -> Vt transposed bf16 [512][8192]
// 128x128 tile; 8 waves as 2(wr) x 4(wc), each 64x32 (acc[4][2]).
// ---------------------------------------------------------------------------
__global__ __launch_bounds__(512, 4) void gemm_mfma(
    const float* __restrict__ X, const short* __restrict__ Bt,
    short* __restrict__ Yh, short* __restrict__ Yl, short* __restrict__ Vt)
{
    // [buf][plane]: 0=Ahi 1=Alo 2=B0(Ghi/Vhi) 3=B1(Glo); 8KB planes, 64KB total
    __shared__ short lds[2][4][128 * 32];

    const int lin = blockIdx.x;              // 0..511
    const int xcd = lin & 7;
    const int s   = lin >> 3;                // 0..63
    int mt, nt;
    if (s < 32) {                            // Y blocks first
        mt = xcd * 8 + (s & 7);
        nt = s >> 3;                         // 0..3
    } else {
        const int v = s - 32;
        mt = xcd * 8 + (v & 7);
        nt = 4 + (v >> 3);                   // 4..7
    }
    const int m0 = mt * 128, n0g = nt * 128;
    const int slab = nt >> 2;                // 0=Y, 1=V

    const int tid = threadIdx.x;
    const int ln  = tid & 63;
    const int wid = tid >> 6;                // 0..7
    const int wr = wid >> 2, wc = wid & 3;   // 2 x 4 waves
    const int lrow = ln & 15;
    const int lkb  = ln >> 4;                // 0..3

    fx4 acc[4][2] = {};

    // A staging geometry: thread -> (row, 8-elem chunk)
    const int ar = tid >> 2;                 // 0..127
    const int aj = tid & 3;                  // chunk 0..3
    const int aoff = ar * 32 + (aj ^ fsw(ar)) * 8;   // swizzled LDS offset
    const float* xrow = X + (size_t)(m0 + ar) * 512 + aj * 8;

    // B staging geometry (pre-swizzled global source, linear LDS dest)
    const int bnr = tid >> 2, bjj = tid & 3;
    const int bjs = bjj ^ fsw(bnr);
    const size_t bsrc = (size_t)(n0g + bnr) * 1024 + bjs * 8;

    auto stageB = [&](int bi, int k0) {
        __builtin_amdgcn_global_load_lds(
            (const __attribute__((address_space(1))) unsigned int*)(Bt + bsrc + k0),
            (__attribute__((address_space(3))) unsigned int*)(&lds[bi][2][tid * 8]), 16, 0, 0);
        if (slab == 0)
            __builtin_amdgcn_global_load_lds(
                (const __attribute__((address_space(1))) unsigned int*)(Bt + bsrc + 512 + k0),
                (__attribute__((address_space(3))) unsigned int*)(&lds[bi][3][tid * 8]), 16, 0, 0);
    };
    auto writeA = [&](int bi, const float4& f0, const float4& f1) {
        const float xs[8] = {f0.x, f0.y, f0.z, f0.w, f1.x, f1.y, f1.z, f1.w};
        union { bs8 v; unsigned short u[8]; } hi, lo;
        #pragma unroll
        for (int e = 0; e < 8; ++e) {
            const unsigned short h = f2bf(xs[e]);
            hi.u[e] = h;
            lo.u[e] = f2bf(xs[e] - bf2f(h));
        }
        *(bs8*)(&lds[bi][0][aoff]) = hi.v;
        if (slab == 0) *(bs8*)(&lds[bi][1][aoff]) = lo.v;
    };
    auto compute = [&](int bi) {
        bs8 ah[4], al[4], b0[2], b1[2];
        #pragma unroll
        for (int mf = 0; mf < 4; ++mf) {
            const int m = wr * 64 + mf * 16 + lrow;
            const int off = m * 32 + ((lkb ^ fsw(m)) * 8);
            ah[mf] = *(const bs8*)(&lds[bi][0][off]);
            if (slab == 0) al[mf] = *(const bs8*)(&lds[bi][1][off]);
        }
        #pragma unroll
        for (int nf = 0; nf < 2; ++nf) {
            const int n = wc * 32 + nf * 16 + lrow;
            const int off = n * 32 + ((lkb ^ fsw(n)) * 8);
            b0[nf] = *(const bs8*)(&lds[bi][2][off]);
            if (slab == 0) b1[nf] = *(const bs8*)(&lds[bi][3][off]);
        }
        #pragma unroll
        for (int mf = 0; mf < 4; ++mf)
            #pragma unroll
            for (int nf = 0; nf < 2; ++nf) {
                acc[mf][nf] = __builtin_amdgcn_mfma_f32_16x16x32_bf16(
                    ah[mf], b0[nf], acc[mf][nf], 0, 0, 0);
                if (slab == 0) {
                    acc[mf][nf] = __builtin_amdgcn_mfma_f32_16x16x32_bf16(
                        al[mf], b0[nf], acc[mf][nf], 0, 0, 0);
                    acc[mf][nf] = __builtin_amdgcn_mfma_f32_16x16x32_bf16(
                        ah[mf], b1[nf], acc[mf][nf], 0, 0, 0);
                }
            }
    };

    // prologue: chunk 0 into buf 0
    {
        const float4 f0 = *(const float4*)xrow;
        const float4 f1 = *(const float4*)(xrow + 4);
        stageB(0, 0);
        writeA(0, f0, f1);
    }
    __syncthreads();

    #pragma unroll 2
    for (int it = 0; it < 16; ++it) {
        const int bi = it & 1;
        float4 n0, n1;
        if (it < 15) {
            const float* p = xrow + (it + 1) * 32;
            n0 = *(const float4*)p;
            n1 = *(const float4*)(p + 4);
            stageB(bi ^ 1, (it + 1) * 32);
        }
        compute(bi);
        if (it < 15) writeA(bi ^ 1, n0, n1);
        __syncthreads();
    }

    if (slab == 0) {
        // Y epilogue: split into Yh/Yl bf16 planes
        #pragma unroll
        for (int mf = 0; mf < 4; ++mf) {
            #pragma unroll
            for (int nf = 0; nf < 2; ++nf) {
                const int col = n0g + wc * 32 + nf * 16 + lrow;
                #pragma unroll
                for (int r = 0; r < 4; ++r) {
                    const int row = m0 + wr * 64 + mf * 16 + lkb * 4 + r;
                    const float v = acc[mf][nf][r];
                    const unsigned short h = f2bf(v);
                    Yh[(size_t)row * 512 + col] = (short)h;
                    Yl[(size_t)row * 512 + col] = (short)f2bf(v - bf2f(h));
                }
            }
        }
    } else {
        // V epilogue: transposed store Vt[d][token], 4 rows -> one 8B store
        #pragma unroll
        for (int mf = 0; mf < 4; ++mf) {
            #pragma unroll
            for (int nf = 0; nf < 2; ++nf) {
                const int c = (n0g - 512) + wc * 32 + nf * 16 + lrow;   // d
                const int row0 = m0 + wr * 64 + mf * 16 + lkb * 4;
                sh4 v4;
                #pragma unroll
                for (int r = 0; r < 4; ++r) v4[r] = (short)f2bf(acc[mf][nf][r]);
                *(sh4*)(Vt + (size_t)c * 8192 + row0) = v4;
            }
        }
    }
}

// ---------------------------------------------------------------------------
// Kernel 4: banded attention via MFMA — 4 cooperative waves per 16-token
// strip (8 waves/CU).
//   QK: wave w computes K-chunks [4w,4w+4) -> partial S; f32 LDS reduce
//       (padded stride 20; deterministic order).
//   softmax: wave 0 computes + writes Plds.
//   PV: wave w owns d-columns [128w,128w+128); its 8 Vt fragments hoisted
//       at kernel entry.
//   concat copy: each wave copies its own K-chunks' X rows.
//   Band: src<0 slots -> logit 0 exactly (exp(0) in denominator), no V term.
// ---------------------------------------------------------------------------
__global__ __launch_bounds__(256, 1) void attn_mfma(
    const float* __restrict__ X,
    const short* __restrict__ Yh, const short* __restrict__ Yl,
    const short* __restrict__ Vt, float* __restrict__ out)
{
    __shared__ float Sred[4][64][20];   // 20KB, stride-20 pad (16B-aligned)
    __shared__ short Plds[16 * 32];

    const int lin = blockIdx.x;                   // 0..511
    const int strip = (lin & 7) * 64 + (lin >> 3);  // XCD swizzle (512=8x64)
    const int t0 = strip * 16;
    const int bat = t0 >> 10;
    const int tt0 = t0 & 1023;
    const int tid = threadIdx.x;
    const int l  = tid & 63;
    const int w  = tid >> 6;                      // wave 0..3
    const int lr = l & 15;
    const int lg = l >> 4;                        // 0..3

    // ---- hoisted PV B-fragments: wave w covers nf = 8w..8w+8 (OOB reads
    //      hit finite ws bytes only where P=0) ----
    const long svt = (long)bat * 1024 + (tt0 - 15 + lg * 8);
    bs8 bv[8];
    #pragma unroll
    for (int q = 0; q < 8; ++q)
        bv[q] = *(const bs8*)(Vt + (long)((w * 8 + q) * 16 + lr) * 8192 + svt);

    const size_t yrow = (size_t)(t0 + lr) * 512 + lg * 8;
    const int srcl0 = tt0 - 15 + lr;              // local src for j=lr
    const int srcl1 = tt0 + 1 + lr;               // local src for j=lr+16
    const int r0c = srcl0 < 0 ? 0 : srcl0;
    const int r1c = srcl1 > 1023 ? 1023 : srcl1;  // only j=31 (masked) hits 1024
    const size_t xrow0 = ((size_t)(bat * 1024 + r0c)) * 512 + lg * 8;
    const size_t xrow1 = ((size_t)(bat * 1024 + r1c)) * 512 + lg * 8;

    fx4 s0a = {0,0,0,0}, s0b = {0,0,0,0};
    fx4 s1a = {0,0,0,0}, s1b = {0,0,0,0};
    #pragma unroll
    for (int kc = 0; kc < 4; ++kc) {
        const int k0 = (w * 4 + kc) * 32;         // this wave's K-chunks
        const bs8 ah = *(const bs8*)(Yh + yrow + k0);
        const bs8 al = *(const bs8*)(Yl + yrow + k0);
        const float4 p0a = *(const float4*)(X + xrow0 + k0);
        const float4 p0b = *(const float4*)(X + xrow0 + k0 + 4);
        const float4 p1a = *(const float4*)(X + xrow1 + k0);
        const float4 p1b = *(const float4*)(X + xrow1 + k0 + 4);
        const float x0s[8] = {p0a.x,p0a.y,p0a.z,p0a.w,p0b.x,p0b.y,p0b.z,p0b.w};
        const float x1s[8] = {p1a.x,p1a.y,p1a.z,p1a.w,p1b.x,p1b.y,p1b.z,p1b.w};
        union { bs8 v; unsigned short u[8]; } bh0, bl0, bh1, bl1;
        #pragma unroll
        for (int e = 0; e < 8; ++e) {
            unsigned short h = f2bf(x0s[e]);
            bh0.u[e] = h; bl0.u[e] = f2bf(x0s[e] - bf2f(h));
            h = f2bf(x1s[e]);
            bh1.u[e] = h; bl1.u[e] = f2bf(x1s[e] - bf2f(h));
        }
        s0a = __builtin_amdgcn_mfma_f32_16x16x32_bf16(ah, bh0.v, s0a, 0, 0, 0);
        s0b = __builtin_amdgcn_mfma_f32_16x16x32_bf16(al, bh0.v, s0b, 0, 0, 0);
        s0b = __builtin_amdgcn_mfma_f32_16x16x32_bf16(ah, bl0.v, s0b, 0, 0, 0);
        s1a = __builtin_amdgcn_mfma_f32_16x16x32_bf16(ah, bh1.v, s1a, 0, 0, 0);
        s1b = __builtin_amdgcn_mfma_f32_16x16x32_bf16(al, bh1.v, s1b, 0, 0, 0);
        s1b = __builtin_amdgcn_mfma_f32_16x16x32_bf16(ah, bl1.v, s1b, 0, 0, 0);

        // concat copy: rows t0..t0+15 from the same loads (exact f32)
        if (lr == 15) {               // xrow0 == row t0
            float* o = out + (size_t)t0 * 1024 + k0 + lg * 8;
            *(float4*)o       = p0a;
            *(float4*)(o + 4) = p0b;
        } else {                      // xrow1 == row t0+1+lr  (lr<15)
            float* o = out + (size_t)(t0 + 1 + lr) * 1024 + k0 + lg * 8;
            *(float4*)o       = p1a;
            *(float4*)(o + 4) = p1b;
        }
    }

    // ---- cross-wave S reduction via LDS (deterministic order) ----
    {
        float* sp = &Sred[w][l][0];
        *((fx4*)sp + 0) = s0a; *((fx4*)sp + 1) = s0b;
        *((fx4*)sp + 2) = s1a; *((fx4*)sp + 3) = s1b;
    }
    __syncthreads();
    if (w == 0) {
        #pragma unroll
        for (int ow = 1; ow < 4; ++ow) {
            const float* op = &Sred[ow][l][0];
            s0a += *((const fx4*)op + 0); s0b += *((const fx4*)op + 1);
            s1a += *((const fx4*)op + 2); s1b += *((const fx4*)op + 3);
        }
        // ---- band mask + softmax (per lane: 4 rows x 2 cols) ----
        #pragma unroll
        for (int r = 0; r < 4; ++r) {
            const int i = lg * 4 + r;
            const int d0 = lr - i;            // w-offset for j=lr
            const int d1 = lr + 16 - i;       // w-offset for j=lr+16
            const bool in0 = (d0 >= 0) && (d0 <= 15);
            const bool in1 = (d1 >= 0) && (d1 <= 15);
            const bool z0 = srcl0 < 0;        // src<0 -> logit 0 exactly
            float v0 = z0 ? 0.0f : (s0a[r] + s0b[r]);
            float v1 = s1a[r] + s1b[r];
            v0 = in0 ? v0 : -3.0e38f;
            v1 = in1 ? v1 : -3.0e38f;
            float m = fmaxf(v0, v1);
            #pragma unroll
            for (int st = 1; st < 16; st <<= 1) m = fmaxf(m, __shfl_xor(m, st, 64));
            const float e0 = in0 ? __expf(v0 - m) : 0.0f;
            const float e1 = in1 ? __expf(v1 - m) : 0.0f;
            float den = e0 + e1;
            #pragma unroll
            for (int st = 1; st < 16; st <<= 1) den += __shfl_xor(den, st, 64);
            const float inv = 1.0f / den;
            const float p0 = (in0 && !z0) ? e0 * inv : 0.0f;
            const float p1 = in1 ? e1 * inv : 0.0f;
            Plds[i * 32 + lr]      = (short)f2bf(p0);
            Plds[i * 32 + lr + 16] = (short)f2bf(p1);
        }
    }
    __syncthreads();

    // ---- PV: answer(16x512) = P(16x32) @ V'_window(32x512); wave w owns
    //      d-columns [128w, 128w+128), B pre-loaded ----
    const bs8 pa = *(const bs8*)(Plds + lr * 32 + lg * 8);
    #pragma unroll
    for (int q = 0; q < 8; ++q) {
        const int d = (w * 8 + q) * 16 + lr;
        fx4 c = {0, 0, 0, 0};
        c = __builtin_amdgcn_mfma_f32_16x16x32_bf16(pa, bv[q], c, 0, 0, 0);
        #pragma unroll
        for (int r = 0; r < 4; ++r)
            out[(size_t)(t0 + lg * 4 + r) * 1024 + 512 + d] = c[r];
    }
}

// ---------------------------------------------------------------------------
extern "C" void kernel_launch(void* const* d_in, const int* in_sizes, int n_in,
                              void* d_out, int out_size, void* d_ws, size_t ws_size,
                              hipStream_t stream)
{
    const float* X  = (const float*)d_in[0];
    const float* Mw = (const float*)d_in[1];
    const float* Cw = (const float*)d_in[2];
    const float* Vw = (const float*)d_in[3];
    float* out = (float*)d_out;

    // ws layout (34 MB total), Vt LAST (OOB guard reads land in Yl):
    short* Bt = (short*)d_ws;                                   // 2 MB
    float* Gp = (float*)(Bt + (size_t)1024 * 1024);             // 8 MB
    short* Yh = (short*)(Gp + (size_t)8 * 512 * 512);           // 8 MB
    short* Yl = Yh + (size_t)BT * 512;                          // 8 MB
    short* Vt = Yl + (size_t)BT * 512;                          // 8 MB

    wprep<<<576, 256, 0, stream>>>(Mw, Cw, Vw, Gp, Bt);
    pack_g<<<256, 256, 0, stream>>>(Gp, Bt);
    gemm_mfma<<<512, 512, 0, stream>>>(X, Bt, Yh, Yl, Vt);
    attn_mfma<<<512, 256, 0, stream>>>(X, Yh, Yl, Vt, out);
}